// Round 1
// baseline (403.123 us; speedup 1.0000x reference)
//
#include <hip/hip_runtime.h>
#include <hip/hip_bf16.h>

typedef __attribute__((ext_vector_type(8))) __bf16 bf16x8;
typedef __attribute__((ext_vector_type(4))) float f32x4;

#define NN 20000
#define LL 64

// Pack W1 (64x128 f32, row-major) -> w1p[c][k] bf16 (c<128, k<64)
// Pack W2 (128x64 f32, row-major) -> w2p[c][k] bf16 (c<64, k<128)
__global__ void pack_w(const float* __restrict__ W1, const float* __restrict__ W2,
                       __bf16* __restrict__ w1p, __bf16* __restrict__ w2p) {
    int i = blockIdx.x * 256 + threadIdx.x;   // grid 32 * 256 = 8192
    if (i < 64 * 128) {
        int c = i >> 6, k = i & 63;
        w1p[i] = (__bf16)W1[k * 128 + c];
        int c2 = i >> 7, k2 = i & 127;
        w2p[i] = (__bf16)W2[k2 * 64 + c2];
    }
}

__global__ __launch_bounds__(256) void vpsl_main(
    const float* __restrict__ S, const int* __restrict__ mask,
    const int* __restrict__ gidx, const int* __restrict__ rvalid,
    const __bf16* __restrict__ w1p, const __bf16* __restrict__ w2p,
    const float* __restrict__ b1, const float* __restrict__ b2,
    const float* __restrict__ W3, const float* __restrict__ b3,
    const float* __restrict__ W4, const float* __restrict__ b4,
    float* __restrict__ out)
{
    __shared__ __align__(16) __bf16 h_lds[4][16][136];  // per-wave h tile, pitch 136 (16B aligned rows, 2-way max bank alias)
    __shared__ float mid_s[64];
    __shared__ int   gi_s[64];
    __shared__ int   rv_s[64];
    __shared__ float red_s[128];

    const int n    = blockIdx.x;
    const int tid  = threadIdx.x;
    const int w    = tid >> 6;     // wave 0..3 -> rows 16w..16w+15
    const int lane = tid & 63;
    const int g    = lane >> 4;    // 16-lane group
    const int lc   = lane & 15;

    if (tid < 64) {
        gi_s[tid] = gidx[(size_t)n * 64 + tid];
        rv_s[tid] = rvalid[(size_t)n * 64 + tid];
    }

    // per-lane bias values (uniform across nodes)
    float b1v[8];
#pragma unroll
    for (int t = 0; t < 8; ++t) b1v[t] = b1[t * 16 + lc];
    float b2v[4];
#pragma unroll
    for (int t = 0; t < 4; ++t) b2v[t] = b2[t * 16 + lc];

    // ---------------- fc1: h = relu(S @ W1 + b1) ----------------
    // A-frag: row = lane&15 (global row 16w+lc), k = ks*32 + g*8 + [0..8)
    const float* srow = S + ((size_t)n * 64 + 16 * w + lc) * 64;
    bf16x8 af[2];
#pragma unroll
    for (int ks = 0; ks < 2; ++ks) {
        const float4* p = reinterpret_cast<const float4*>(srow + ks * 32 + g * 8);
        float4 x0 = p[0], x1 = p[1];
        bf16x8 a;
        a[0] = (__bf16)x0.x; a[1] = (__bf16)x0.y; a[2] = (__bf16)x0.z; a[3] = (__bf16)x0.w;
        a[4] = (__bf16)x1.x; a[5] = (__bf16)x1.y; a[6] = (__bf16)x1.z; a[7] = (__bf16)x1.w;
        af[ks] = a;
    }

    f32x4 hacc[8];
#pragma unroll
    for (int t = 0; t < 8; ++t) hacc[t] = (f32x4){0.f, 0.f, 0.f, 0.f};

#pragma unroll
    for (int ks = 0; ks < 2; ++ks) {
#pragma unroll
        for (int t = 0; t < 8; ++t) {
            bf16x8 bf = *reinterpret_cast<const bf16x8*>(w1p + (t * 16 + lc) * 64 + ks * 32 + g * 8);
            hacc[t] = __builtin_amdgcn_mfma_f32_16x16x32_bf16(af[ks], bf, hacc[t], 0, 0, 0);
        }
    }

    // h (bias+relu, bf16) -> per-wave LDS. D-layout: row=4g+j, col=16t+lc
#pragma unroll
    for (int t = 0; t < 8; ++t) {
#pragma unroll
        for (int j = 0; j < 4; ++j) {
            float v = hacc[t][j] + b1v[t];
            v = v > 0.f ? v : 0.f;
            h_lds[w][4 * g + j][16 * t + lc] = (__bf16)v;
        }
    }
    __syncthreads();   // covers h_lds writes and gi_s/rv_s

    // ---------------- fc2: logits = h @ W2 + b2 ----------------
    f32x4 lacc[4];
#pragma unroll
    for (int t = 0; t < 4; ++t) lacc[t] = (f32x4){0.f, 0.f, 0.f, 0.f};
#pragma unroll
    for (int ks = 0; ks < 4; ++ks) {
        bf16x8 ah = *reinterpret_cast<const bf16x8*>(&h_lds[w][lc][ks * 32 + g * 8]);
#pragma unroll
        for (int t = 0; t < 4; ++t) {
            bf16x8 bf = *reinterpret_cast<const bf16x8*>(w2p + (t * 16 + lc) * 128 + ks * 32 + g * 8);
            lacc[t] = __builtin_amdgcn_mfma_f32_16x16x32_bf16(ah, bf, lacc[t], 0, 0, 0);
        }
    }

    // ---------------- masked softmax + gather ----------------
#pragma unroll
    for (int j = 0; j < 4; ++j) {
        const int row = 16 * w + 4 * g + j;
        const int* mrow = mask + ((size_t)n * 64 + row) * 64 + lc;
        int m[4];
#pragma unroll
        for (int t = 0; t < 4; ++t) m[t] = mrow[16 * t];
        float l[4];
#pragma unroll
        for (int t = 0; t < 4; ++t) l[t] = m[t] ? (lacc[t][j] + b2v[t]) : -3.0e38f;
        float mx = fmaxf(fmaxf(l[0], l[1]), fmaxf(l[2], l[3]));
#pragma unroll
        for (int off = 1; off < 16; off <<= 1) mx = fmaxf(mx, __shfl_xor(mx, off));
        float e[4];
#pragma unroll
        for (int t = 0; t < 4; ++t) e[t] = m[t] ? __expf(l[t] - mx) : 0.f;
        float s = (e[0] + e[1]) + (e[2] + e[3]);
#pragma unroll
        for (int off = 1; off < 16; off <<= 1) s += __shfl_xor(s, off);
        const int gi = gi_s[row];
        float sel = 0.f;
#pragma unroll
        for (int t = 0; t < 4; ++t) sel += (((gi >> 4) == t) && ((gi & 15) == lc)) ? e[t] : 0.f;
#pragma unroll
        for (int off = 1; off < 16; off <<= 1) sel += __shfl_xor(sel, off);
        if (lc == 0) {
            float mv = (rv_s[row] != 0 && s > 0.f) ? (sel / s) : 0.f;
            mid_s[row] = mv;
        }
    }
    __syncthreads();

    // ---------------- fc3 + fc4 (f32) ----------------
    if (tid < 128) {
        float acc = 0.f;
#pragma unroll 8
        for (int k = 0; k < 64; ++k) acc += mid_s[k] * W3[k * 128 + tid];
        acc += b3[tid];
        acc = acc > 0.f ? acc : 0.f;
        red_s[tid] = acc * W4[tid];
    }
    __syncthreads();
    if (tid < 64) {
        float v = red_s[tid] + red_s[tid + 64];
#pragma unroll
        for (int off = 1; off < 64; off <<= 1) v += __shfl_xor(v, off);
        if (tid == 0) {
            float z = v + b4[0];
            out[n] = 1.f / (1.f + __expf(-z));
        }
    }
}

extern "C" void kernel_launch(void* const* d_in, const int* in_sizes, int n_in,
                              void* d_out, int out_size, void* d_ws, size_t ws_size,
                              hipStream_t stream) {
    const float* S    = (const float*)d_in[0];
    const int*   mask = (const int*)d_in[1];
    const int*   gidx = (const int*)d_in[2];
    const int*   rv   = (const int*)d_in[3];
    const float* W1   = (const float*)d_in[4];
    const float* b1   = (const float*)d_in[5];
    const float* W2   = (const float*)d_in[6];
    const float* b2   = (const float*)d_in[7];
    const float* W3   = (const float*)d_in[8];
    const float* b3   = (const float*)d_in[9];
    const float* W4   = (const float*)d_in[10];
    const float* b4   = (const float*)d_in[11];
    float* out = (float*)d_out;

    __bf16* w1p = (__bf16*)d_ws;              // 128*64 bf16 = 16 KB
    __bf16* w2p = w1p + 64 * 128;             // 64*128 bf16 = 16 KB

    hipLaunchKernelGGL(pack_w, dim3(32), dim3(256), 0, stream, W1, W2, w1p, w2p);
    hipLaunchKernelGGL(vpsl_main, dim3(NN), dim3(256), 0, stream,
                       S, mask, gidx, rv, w1p, w2p, b1, b2, W3, b3, W4, b4, out);
}